// Round 16
// baseline (339.532 us; speedup 1.0000x reference)
//
#include <hip/hip_runtime.h>
#include <hip/hip_fp16.h>

typedef short v8s __attribute__((ext_vector_type(8)));
typedef float v4f __attribute__((ext_vector_type(4)));
typedef float v2f __attribute__((ext_vector_type(2)));

#define NSP 32768
#define XSTR 2056            // bytes per w-location in Xbuf (8B aligned, bank-staggered)
#define WS_ZP_B  65536ull    // zp region: 4 chunks x 2048 x 256 fp32 (8.4 MB)
#define WS_ATT_B 16777216ull // att region: 65536 wave-slices x 512 B (33.5 MB)

__device__ __forceinline__ unsigned short f2bf(float f) {
  union { float f; unsigned u; } v; v.f = f;
  unsigned r = v.u + 0x7fffu + ((v.u >> 16) & 1u);
  return (unsigned short)(r >> 16);
}
__device__ __forceinline__ unsigned pk(float a, float b) {
  return (unsigned)f2bf(a) | ((unsigned)f2bf(b) << 16);
}
__device__ __forceinline__ unsigned pkh(float a, float b) {
  union { __half2 h; unsigned u; } c; c.h = __floats2half2_rn(a, b); return c.u;
}
__device__ __forceinline__ float2 uph(unsigned u) {
  union { unsigned u; __half2 h; } c; c.u = u; return __half22float2(c.h);
}

union UF8 { v8s v; unsigned u[4]; uint4 q; };

// k-map convention used CONSISTENTLY for every A and B fragment (errors cancel):
// frag element j of lane (i16 + 16*g) <-> k = 16*(j>>2) + 4*g + (j&3)

__global__ __launch_bounds__(512) void prep_kernel(
    const float* __restrict__ Wk, const float* __restrict__ bk,
    const float* __restrict__ Wq, const float* __restrict__ bq,
    const float* __restrict__ Wv, unsigned* __restrict__ ws) {
  __shared__ float sWk[4096], sWq[4096], sWv[4096], sbk[64], sbq[64];
  for (int i = threadIdx.x; i < 4096; i += 512) { sWk[i] = Wk[i]; sWq[i] = Wq[i]; sWv[i] = Wv[i]; }
  if (threadIdx.x < 64) { sbk[threadIdx.x] = bk[threadIdx.x]; sbq[threadIdx.x] = bq[threadIdx.x]; }
  __syncthreads();
  for (int task = threadIdx.x; task < 18 * 64; task += 512) {
    int f = task >> 6, lane = task & 63;
    int i16 = lane & 15, g = lane >> 4;
    unsigned short e[8];
    #pragma unroll
    for (int j = 0; j < 8; ++j) {
      int k = (((j >> 2) << 4) + 4 * g + (j & 3));
      float acc = 0.f;
      if (f < 8) {
        int row = ((f >> 1) << 4) + i16;
        int cc  = ((f & 1) << 5) + k;
        for (int a = 0; a < 64; ++a) acc += sWk[a * 64 + row] * sWq[a * 64 + cc];
      } else if (f < 10) {
        int c = ((f - 8) << 5) + k;
        if (i16 == 0)      { for (int a = 0; a < 64; ++a) acc += sWk[a * 64 + c] * sbq[a]; }
        else if (i16 == 1) { for (int a = 0; a < 64; ++a) acc += sbk[a] * sWq[a * 64 + c]; }
      } else {
        int c  = (((f - 10) >> 1) << 4) + i16;
        int cp = (((f - 10) & 1) << 5) + k;
        acc = sWv[c * 64 + cp];
      }
      e[j] = f2bf(acc);
    }
    unsigned* dst = ws + (size_t)(f * 64 + lane) * 4;
    dst[0] = e[0] | ((unsigned)e[1] << 16);
    dst[1] = e[2] | ((unsigned)e[3] << 16);
    dst[2] = e[4] | ((unsigned)e[5] << 16);
    dst[3] = e[6] | ((unsigned)e[7] << 16);
  }
  if (threadIdx.x == 0) {
    float beta = 0.f;
    for (int a = 0; a < 64; ++a) beta += sbk[a] * sbq[a];
    ((float*)ws)[18 * 256] = beta;
  }
}

#define S2L 0.18033688011112042f  /* (1/8) * log2(e) */

// pass1 grid 256: XCD = bid%8 = (b,dc)
#define DECODE256() \
  int bid = (int)blockIdx.x; \
  int b = bid & 1, dc = (bid >> 1) & 3, h = bid >> 3; \
  const int d0 = dc << 3; \
  const size_t base0 = (size_t)b * 33554432 + h * 32;

// pass2 grid 1024: XCD = bid%8 = (b, dcc&3); whp partners (bit 3) share an XCD
#define DECODE1024() \
  int bid = (int)blockIdx.x; \
  int b   = bid & 1; \
  int whp = (bid >> 3) & 1; \
  int dcc = ((bid >> 1) & 3) | (((bid >> 4) & 1) << 2); \
  int h   = bid >> 5; \
  const int d0 = dcc << 2; \
  const size_t base0 = (size_t)b * 33554432 + h * 32 + whp * 16;

// 32-loc half-slice staging (pass1, 512 thr): 32 regs peak; every issueH is
// consumed by the next writeH before another issueH runs (R11 lesson)
#define STAGE_DEFS() \
  const int w2 = tid & 15; \
  const int rp0 = tid >> 4; \
  v2f sA[8], sB[8]; \
  auto issueH = [&](int d, int half) { \
    const float* xp = x + base0 + (size_t)d * 1024; \
    _Pragma("unroll") \
    for (int i = 0; i < 8; ++i) { \
      int rp = half * 256 + (i << 5) + rp0; \
      const float* r0 = xp + (size_t)(2 * rp) * NSP + 2 * w2; \
      sA[i] = *(const v2f*)r0; \
      sB[i] = *(const v2f*)(r0 + NSP); \
    } \
  }; \
  auto writeH = [&](unsigned char* BUF, int half) { \
    _Pragma("unroll") \
    for (int i = 0; i < 8; ++i) { \
      int rp = half * 256 + (i << 5) + rp0; \
      int t = rp >> 5, c = (rp & 31) << 1; \
      int off = (t << 7) + (((c << 1)) ^ ((t & 7) << 4)); \
      *(unsigned*)(&BUF[(2 * w2) * XSTR + off])     = pk(sA[i].x, sB[i].x); \
      *(unsigned*)(&BUF[(2 * w2 + 1) * XSTR + off]) = pk(sA[i].y, sB[i].y); \
    } \
  };

// 16-loc half-slice staging (pass2, 512 thr): 16 regs peak
#define STAGE16_DEFS() \
  const int w2 = tid & 7; \
  const int rp0 = tid >> 3; \
  v2f sA[4], sB[4]; \
  auto issueH = [&](int d, int half) { \
    const float* xp = x + base0 + (size_t)d * 1024; \
    _Pragma("unroll") \
    for (int i = 0; i < 4; ++i) { \
      int rp = half * 256 + (i << 6) + rp0; \
      const float* r0 = xp + (size_t)(2 * rp) * NSP + 2 * w2; \
      sA[i] = *(const v2f*)r0; \
      sB[i] = *(const v2f*)(r0 + NSP); \
    } \
  }; \
  auto writeH = [&](unsigned char* BUF, int half) { \
    _Pragma("unroll") \
    for (int i = 0; i < 4; ++i) { \
      int rp = half * 256 + (i << 6) + rp0; \
      int t = rp >> 5, c = (rp & 31) << 1; \
      int off = (t << 7) + (((c << 1)) ^ ((t & 7) << 4)); \
      *(unsigned*)(&BUF[(2 * w2) * XSTR + off])     = pk(sA[i].x, sB[i].x); \
      *(unsigned*)(&BUF[(2 * w2 + 1) * XSTR + off]) = pk(sA[i].y, sB[i].y); \
    } \
  };

#define LOADX_DEF() \
  auto loadX = [&](const unsigned char* BUF, int loc, v8s fX[2]) { \
    const unsigned char* bp = &BUF[loc * XSTR + (i16 << 7)]; \
    const int sw = (i16 & 7) << 4; \
    _Pragma("unroll") \
    for (int kc = 0; kc < 2; ++kc) { \
      union { v8s v; unsigned long long dd[2]; } u; \
      int o = (kc << 6) + (g << 3); \
      u.dd[0] = *(const unsigned long long*)(bp + (o ^ sw)); \
      u.dd[1] = *(const unsigned long long*)(bp + ((o + 32) ^ sw)); \
      fX[kc] = u.v; \
    } \
  };

// weight fragments read from LDS per use
#define LDF_DEF() \
  auto ldf = [&](int f) -> v8s { \
    union { v8s v; uint4 q; } u; \
    u.q = *(const uint4*)&Wm[(f << 8) + (lane << 2)]; \
    return u.v; \
  };

#define ATTOF_DEF() \
  auto attOf = [&](const v8s fX[2]) -> v4f { \
    v4f accW[4]; \
    _Pragma("unroll") \
    for (int tr = 0; tr < 4; ++tr) { \
      v8s m0 = ldf(2 * tr), m1 = ldf(2 * tr + 1); \
      v4f a = {0.f, 0.f, 0.f, 0.f}; \
      a = __builtin_amdgcn_mfma_f32_16x16x32_bf16(m0, fX[0], a, 0, 0, 0); \
      a = __builtin_amdgcn_mfma_f32_16x16x32_bf16(m1, fX[1], a, 0, 0, 0); \
      accW[tr] = a; \
    } \
    v8s u0 = ldf(8), u1 = ldf(9); \
    v4f au = {0.f, 0.f, 0.f, 0.f}; \
    au = __builtin_amdgcn_mfma_f32_16x16x32_bf16(u0, fX[0], au, 0, 0, 0); \
    au = __builtin_amdgcn_mfma_f32_16x16x32_bf16(u1, fX[1], au, 0, 0, 0); \
    float a1v = au[0] + beta; \
    float a2v = au[1]; \
    float a2s = __shfl(a2v, i16); \
    v4f att; \
    _Pragma("unroll") \
    for (int j = 0; j < 4; ++j) att[j] = __shfl(a1v, 4 * g + j) + a2s; \
    _Pragma("unroll") \
    for (int kc = 0; kc < 2; ++kc) { \
      UF8 w; \
      w.u[0] = pk(accW[2 * kc][0], accW[2 * kc][1]); \
      w.u[1] = pk(accW[2 * kc][2], accW[2 * kc][3]); \
      w.u[2] = pk(accW[2 * kc + 1][0], accW[2 * kc + 1][1]); \
      w.u[3] = pk(accW[2 * kc + 1][2], accW[2 * kc + 1][3]); \
      att = __builtin_amdgcn_mfma_f32_16x16x32_bf16(fX[kc], w.v, att, 0, 0, 0); \
    } \
    return att; \
  };

// feat MFMA for one c-quarter (tn literal!) -> Fb (stride 16, XOR on w bits[3:2])
#define FEATQ16(tn, FB) do { \
  _Pragma("unroll") \
  for (int l = 0; l < 2; ++l) { \
    int wq = 2 * wv + l; \
    UF8 fP; fP.u[0] = Pp[l][0]; fP.u[1] = Pp[l][1]; fP.u[2] = 0; fP.u[3] = 0; \
    UF8 fV; fV.u[0] = vp[l][2 * (tn)]; fV.u[1] = vp[l][2 * (tn) + 1]; fV.u[2] = 0; fV.u[3] = 0; \
    v4f ft = {0.f, 0.f, 0.f, 0.f}; \
    ft = __builtin_amdgcn_mfma_f32_16x16x32_bf16(fP.v, fV.v, ft, 0, 0, 0); \
    _Pragma("unroll") \
    for (int j = 0; j < 4; ++j) { \
      int r = (4 * g + j) * 16 + i16; \
      (FB)[r * 16 + (wq ^ (((g + (i16 >> 1)) & 3) << 2))] = ft[j]; \
    } \
  } \
} while (0)

// ---------------- pass 1: Z partials + att(f16, pre-scaled) store (unchanged R15) ----------------
__global__ __launch_bounds__(512) void pass1_z(
    const float* __restrict__ x, const unsigned* __restrict__ ws,
    float* __restrict__ zp, unsigned* __restrict__ attw) {
  __shared__ __align__(16) unsigned char Xd[2][65792];      // 131584 B
  __shared__ unsigned Wm[2560];                             // 10240 B  (total 141824)

  const int tid = (int)threadIdx.x;
  const int lane = tid & 63, wv = tid >> 6;
  const int i16 = lane & 15, g = lane >> 4;
  DECODE256();

  for (int o = tid; o < 2560; o += 512) Wm[o] = ws[o];
  const float beta = ((const float*)ws)[4608];

  STAGE_DEFS();
  LOADX_DEF();
  LDF_DEF();
  ATTOF_DEF();

  auto doLoc = [&](const unsigned char* cur, int d, int l, float Zl[4]) {
    v8s fX[2]; loadX(cur, 4 * wv + l, fX);
    v4f att = attOf(fX);
    float s0 = att[0] * S2L, s1 = att[1] * S2L;
    float s2 = att[2] * S2L, s3 = att[3] * S2L;
    Zl[0] += exp2f(s0); Zl[1] += exp2f(s1);
    Zl[2] += exp2f(s2); Zl[3] += exp2f(s3);
    uint2 av; av.x = pkh(s0, s1); av.y = pkh(s2, s3);
    const size_t ls = ((size_t)((b << 5) + h) * 32 + d) * 32 + (4 * wv + l);
    *(uint2*)(attw + ls * 128 + lane * 2) = av;
  };

  float Z[4][4] = {};
  issueH(d0, 0); writeH(Xd[0], 0);
  issueH(d0, 1); writeH(Xd[0], 1);
  __syncthreads();
  for (int ii = 0; ii < 8; ++ii) {
    const int d = d0 + ii;
    unsigned char* cur = Xd[ii & 1];
    unsigned char* nxt = Xd[(ii & 1) ^ 1];
    if (ii < 7) issueH(d + 1, 0);
    doLoc(cur, d, 0, Z[0]);
    doLoc(cur, d, 1, Z[1]);
    if (ii < 7) { writeH(nxt, 0); issueH(d + 1, 1); }
    doLoc(cur, d, 2, Z[2]);
    doLoc(cur, d, 3, Z[3]);
    if (ii < 7) writeH(nxt, 1);
    __syncthreads();
  }
  const int locg = b * 1024 + h * 32 + 4 * wv;
  #pragma unroll
  for (int l = 0; l < 4; ++l)
    #pragma unroll
    for (int j = 0; j < 4; ++j)
      zp[(((size_t)dc * 2048 + locg + l) << 8) + (4 * g + j) * 16 + i16] = Z[l][j];
}

// ---------------- pass 2: 16-loc blocks for 2 blocks/CU; att-load, v, feat, out ----------------
__global__ __launch_bounds__(512) void pass2_out(
    const float* __restrict__ x, const float* __restrict__ bv,
    const unsigned* __restrict__ ws, const float* __restrict__ zp,
    const unsigned* __restrict__ attw, float* __restrict__ out) {
  __shared__ __align__(16) unsigned char Xd[2][32896];      // 65792 B (X-stage or FbA+FbB)
  __shared__ unsigned Wm[2048];                             // 8192 B: fWv frags (total 73984)

  const int tid = (int)threadIdx.x;
  const int lane = tid & 63, wv = tid >> 6;
  const int i16 = lane & 15, g = lane >> 4;
  DECODE1024();

  for (int o = tid; o < 2048; o += 512) Wm[o] = ws[2560 + o];
  float bvv[4];
  #pragma unroll
  for (int tn = 0; tn < 4; ++tn) bvv[tn] = bv[i16 + 16 * tn];

  // 1/Z from the 4 pass1 chunk partials (2 locs per wave)
  float iZ[2][4];
  #pragma unroll
  for (int l = 0; l < 2; ++l) {
    const int locg = b * 1024 + h * 32 + whp * 16 + 2 * wv + l;
    #pragma unroll
    for (int j = 0; j < 4; ++j) {
      float s = 0.f;
      #pragma unroll
      for (int c2 = 0; c2 < 4; ++c2)
        s += zp[(((size_t)c2 * 2048 + locg) << 8) + (4 * g + j) * 16 + i16];
      iZ[l][j] = 1.f / s;
    }
  }

  STAGE16_DEFS();
  LOADX_DEF();

  auto lfv = [&](int f) -> v8s {           // fWv fragment f = 2*tn+kc from LDS
    union { v8s v; uint4 q; } u;
    u.q = *(const uint4*)&Wm[(f << 8) + (lane << 2)];
    return u.v;
  };
  auto loadAtt = [&](int d, uint2* dst) {
    #pragma unroll
    for (int l = 0; l < 2; ++l) {
      const size_t ls = ((size_t)((b << 5) + h) * 32 + d) * 32 + whp * 16 + 2 * wv + l;
      dst[l] = *(const uint2*)(attw + ls * 128 + lane * 2);
    }
  };

  auto storeQ = [&](int tn, int d, const float* FB) {
    float* op = out + base0 + (size_t)d * 1024 + (size_t)(16 * tn) * NSP;
    const int w4 = tid & 3, rr = tid >> 2;   // rr in [0,128)
    #pragma unroll
    for (int it = 0; it < 2; ++it) {
      int r = (it << 7) + rr;                // r in [0,256)
      int q = ((r >> 6) + ((r & 15) >> 1)) & 3;
      float4 val = *(const float4*)&FB[r * 16 + 4 * w4];
      *(float4*)(op + (size_t)(((r >> 4) << 6) + (r & 15)) * NSP + 4 * (w4 ^ q)) = val;
    }
  };

  // prologue: stage slice d0 into Xd[0]; load att for d0
  uint2 ar[2];
  loadAtt(d0, ar);
  issueH(d0, 0); writeH(Xd[0], 0);
  issueH(d0, 1); writeH(Xd[0], 1);
  for (int ii = 0; ii < 4; ++ii) {
    const int d = d0 + ii;
    unsigned char* A = Xd[ii & 1];         // current X (read in P/v; Fb after)
    unsigned char* B = Xd[(ii & 1) ^ 1];   // next-slice stage target
    __syncthreads();                       // prologue writes / prev storeQ(3) reads of B done

    // ---- P/v phase: P from preloaded att; v from A; stage d+1 into B ----
    unsigned Pp[2][2], vp[2][8];
    if (ii < 3) issueH(d + 1, 0);
    #pragma unroll
    for (int l = 0; l < 2; ++l) {
      if (l == 1 && ii < 3) { writeH(B, 0); issueH(d + 1, 1); }
      float2 f01 = uph(ar[l].x), f23 = uph(ar[l].y);
      float p0 = exp2f(f01.x) * iZ[l][0], p1 = exp2f(f01.y) * iZ[l][1];
      float p2 = exp2f(f23.x) * iZ[l][2], p3 = exp2f(f23.y) * iZ[l][3];
      Pp[l][0] = pk(p0, p1); Pp[l][1] = pk(p2, p3);
      v8s fX[2]; loadX(A, 2 * wv + l, fX);
      #pragma unroll
      for (int tn = 0; tn < 4; ++tn) {
        v8s wa = lfv(2 * tn), wb = lfv(2 * tn + 1);
        v4f a = {bvv[tn], bvv[tn], bvv[tn], bvv[tn]};
        a = __builtin_amdgcn_mfma_f32_16x16x32_bf16(fX[0], wa, a, 0, 0, 0);
        a = __builtin_amdgcn_mfma_f32_16x16x32_bf16(fX[1], wb, a, 0, 0, 0);
        vp[l][2 * tn] = pk(a[0], a[1]); vp[l][2 * tn + 1] = pk(a[2], a[3]);
      }
    }
    if (ii < 3) writeH(B, 1);
    __syncthreads();                       // A reads done -> Fb overlay on A safe

    float* FbA = (float*)A;
    float* FbB = FbA + 4096;               // 2 x 16 KB within the 32.9 KB buffer
    uint2 arN[2];
    FEATQ16(0, FbA);
    __syncthreads();
    storeQ(0, d, FbA);
    if (ii < 3) loadAtt(d + 1, arN);       // att prefetch flies across FEATQ/store tail
    FEATQ16(1, FbB);
    __syncthreads();
    storeQ(1, d, FbB); FEATQ16(2, FbA);
    __syncthreads();
    storeQ(2, d, FbA); FEATQ16(3, FbB);
    __syncthreads();
    storeQ(3, d, FbB);
    if (ii < 3) { ar[0] = arN[0]; ar[1] = arN[1]; }
  }
}

extern "C" void kernel_launch(void* const* d_in, const int* in_sizes, int n_in,
                              void* d_out, int out_size, void* d_ws, size_t ws_size,
                              hipStream_t stream) {
  const float* x  = (const float*)d_in[0];
  const float* Wk = (const float*)d_in[1];
  const float* bk = (const float*)d_in[2];
  const float* Wq = (const float*)d_in[3];
  const float* bq = (const float*)d_in[4];
  const float* Wv = (const float*)d_in[5];
  const float* bv = (const float*)d_in[6];
  float* out = (float*)d_out;
  unsigned* ws = (unsigned*)d_ws;
  float*    zp   = (float*)((char*)d_ws + WS_ZP_B);
  unsigned* attw = (unsigned*)((char*)d_ws + WS_ATT_B);

  prep_kernel<<<1, 512, 0, stream>>>(Wk, bk, Wq, bq, Wv, ws);
  pass1_z<<<256, 512, 0, stream>>>(x, ws, zp, attw);
  pass2_out<<<1024, 512, 0, stream>>>(x, bv, ws, zp, attw, out);
}

// Round 18
// 273.705 us; speedup vs baseline: 1.2405x; 1.2405x over previous
//
#include <hip/hip_runtime.h>
#include <hip/hip_fp16.h>

typedef short v8s __attribute__((ext_vector_type(8)));
typedef float v4f __attribute__((ext_vector_type(4)));
typedef float v2f __attribute__((ext_vector_type(2)));

#define NSP 32768
#define XSTR 2056            // bytes per w-location in Xbuf (8B aligned, bank-staggered)
#define WS_ZP_B  65536ull    // zp: 4 chunks x 2048 x 256 fp32 (8.4 MB)
#define WS_ATT_B 16777216ull // att: 65536 wave-slices x 512 B (32 MiB)
#define WS_V_B   50331648ull // v:   65536 wave-slices x 2048 B (128 MiB) -> ends 176 MiB

__device__ __forceinline__ unsigned short f2bf(float f) {
  union { float f; unsigned u; } v; v.f = f;
  unsigned r = v.u + 0x7fffu + ((v.u >> 16) & 1u);
  return (unsigned short)(r >> 16);
}
__device__ __forceinline__ unsigned pk(float a, float b) {
  return (unsigned)f2bf(a) | ((unsigned)f2bf(b) << 16);
}
__device__ __forceinline__ unsigned pkh(float a, float b) {
  union { __half2 h; unsigned u; } c; c.h = __floats2half2_rn(a, b); return c.u;
}
__device__ __forceinline__ float2 uph(unsigned u) {
  union { unsigned u; __half2 h; } c; c.u = u; return __half22float2(c.h);
}

union UF8 { v8s v; unsigned u[4]; uint4 q; };

// k-map convention used CONSISTENTLY for every A and B fragment (errors cancel):
// frag element j of lane (i16 + 16*g) <-> k = 16*(j>>2) + 4*g + (j&3)

__global__ __launch_bounds__(512) void prep_kernel(
    const float* __restrict__ Wk, const float* __restrict__ bk,
    const float* __restrict__ Wq, const float* __restrict__ bq,
    const float* __restrict__ Wv, unsigned* __restrict__ ws) {
  __shared__ float sWk[4096], sWq[4096], sWv[4096], sbk[64], sbq[64];
  for (int i = threadIdx.x; i < 4096; i += 512) { sWk[i] = Wk[i]; sWq[i] = Wq[i]; sWv[i] = Wv[i]; }
  if (threadIdx.x < 64) { sbk[threadIdx.x] = bk[threadIdx.x]; sbq[threadIdx.x] = bq[threadIdx.x]; }
  __syncthreads();
  for (int task = threadIdx.x; task < 18 * 64; task += 512) {
    int f = task >> 6, lane = task & 63;
    int i16 = lane & 15, g = lane >> 4;
    unsigned short e[8];
    #pragma unroll
    for (int j = 0; j < 8; ++j) {
      int k = (((j >> 2) << 4) + 4 * g + (j & 3));
      float acc = 0.f;
      if (f < 8) {
        int row = ((f >> 1) << 4) + i16;
        int cc  = ((f & 1) << 5) + k;
        for (int a = 0; a < 64; ++a) acc += sWk[a * 64 + row] * sWq[a * 64 + cc];
      } else if (f < 10) {
        int c = ((f - 8) << 5) + k;
        if (i16 == 0)      { for (int a = 0; a < 64; ++a) acc += sWk[a * 64 + c] * sbq[a]; }
        else if (i16 == 1) { for (int a = 0; a < 64; ++a) acc += sbk[a] * sWq[a * 64 + c]; }
      } else {
        int c  = (((f - 10) >> 1) << 4) + i16;
        int cp = (((f - 10) & 1) << 5) + k;
        acc = sWv[c * 64 + cp];
      }
      e[j] = f2bf(acc);
    }
    unsigned* dst = ws + (size_t)(f * 64 + lane) * 4;
    dst[0] = e[0] | ((unsigned)e[1] << 16);
    dst[1] = e[2] | ((unsigned)e[3] << 16);
    dst[2] = e[4] | ((unsigned)e[5] << 16);
    dst[3] = e[6] | ((unsigned)e[7] << 16);
  }
  if (threadIdx.x == 0) {
    float beta = 0.f;
    for (int a = 0; a < 64; ++a) beta += sbk[a] * sbq[a];
    ((float*)ws)[18 * 256] = beta;
  }
}

#define S2L 0.18033688011112042f  /* (1/8) * log2(e) */

// pass1 grid 256: XCD = bid%8 = (b,dc)
#define DECODE256() \
  int bid = (int)blockIdx.x; \
  int b = bid & 1, dc = (bid >> 1) & 3, h = bid >> 3; \
  const int d0 = dc << 3; \
  const size_t base0 = (size_t)b * 33554432 + h * 32;

// pass2 grid 512
#define DECODE512() \
  int bid = (int)blockIdx.x; \
  int b = bid & 1, dcc = (bid >> 1) & 7, h = bid >> 4; \
  const int d0 = dcc << 2; \
  const size_t base0 = (size_t)b * 33554432 + h * 32;

// half-slice staging (32 regs peak); EVERY issueH consumed by next writeH
#define STAGE_DEFS() \
  const int w2 = tid & 15; \
  const int rp0 = tid >> 4; \
  v2f sA[8], sB[8]; \
  auto issueH = [&](int d, int half) { \
    const float* xp = x + base0 + (size_t)d * 1024; \
    _Pragma("unroll") \
    for (int i = 0; i < 8; ++i) { \
      int rp = half * 256 + (i << 5) + rp0; \
      const float* r0 = xp + (size_t)(2 * rp) * NSP + 2 * w2; \
      sA[i] = *(const v2f*)r0; \
      sB[i] = *(const v2f*)(r0 + NSP); \
    } \
  }; \
  auto writeH = [&](unsigned char* BUF, int half) { \
    _Pragma("unroll") \
    for (int i = 0; i < 8; ++i) { \
      int rp = half * 256 + (i << 5) + rp0; \
      int t = rp >> 5, c = (rp & 31) << 1; \
      int off = (t << 7) + (((c << 1)) ^ ((t & 7) << 4)); \
      *(unsigned*)(&BUF[(2 * w2) * XSTR + off])     = pk(sA[i].x, sB[i].x); \
      *(unsigned*)(&BUF[(2 * w2 + 1) * XSTR + off]) = pk(sA[i].y, sB[i].y); \
    } \
  };

#define LOADX_DEF() \
  auto loadX = [&](const unsigned char* BUF, int loc, v8s fX[2]) { \
    const unsigned char* bp = &BUF[loc * XSTR + (i16 << 7)]; \
    const int sw = (i16 & 7) << 4; \
    _Pragma("unroll") \
    for (int kc = 0; kc < 2; ++kc) { \
      union { v8s v; unsigned long long dd[2]; } u; \
      int o = (kc << 6) + (g << 3); \
      u.dd[0] = *(const unsigned long long*)(bp + (o ^ sw)); \
      u.dd[1] = *(const unsigned long long*)(bp + ((o + 32) ^ sw)); \
      fX[kc] = u.v; \
    } \
  };

// weight fragments (fM 0..7, fUR 8,9, fWv 10..17) read from LDS per use
#define LDF_DEF() \
  auto ldf = [&](int f) -> v8s { \
    union { v8s v; uint4 q; } u; \
    u.q = *(const uint4*)&Wm[(f << 8) + (lane << 2)]; \
    return u.v; \
  };

#define ATTOF_DEF() \
  auto attOf = [&](const v8s fX[2]) -> v4f { \
    v4f accW[4]; \
    _Pragma("unroll") \
    for (int tr = 0; tr < 4; ++tr) { \
      v8s m0 = ldf(2 * tr), m1 = ldf(2 * tr + 1); \
      v4f a = {0.f, 0.f, 0.f, 0.f}; \
      a = __builtin_amdgcn_mfma_f32_16x16x32_bf16(m0, fX[0], a, 0, 0, 0); \
      a = __builtin_amdgcn_mfma_f32_16x16x32_bf16(m1, fX[1], a, 0, 0, 0); \
      accW[tr] = a; \
    } \
    v8s u0 = ldf(8), u1 = ldf(9); \
    v4f au = {0.f, 0.f, 0.f, 0.f}; \
    au = __builtin_amdgcn_mfma_f32_16x16x32_bf16(u0, fX[0], au, 0, 0, 0); \
    au = __builtin_amdgcn_mfma_f32_16x16x32_bf16(u1, fX[1], au, 0, 0, 0); \
    float a1v = au[0] + beta; \
    float a2v = au[1]; \
    float a2s = __shfl(a2v, i16); \
    v4f att; \
    _Pragma("unroll") \
    for (int j = 0; j < 4; ++j) att[j] = __shfl(a1v, 4 * g + j) + a2s; \
    _Pragma("unroll") \
    for (int kc = 0; kc < 2; ++kc) { \
      UF8 w; \
      w.u[0] = pk(accW[2 * kc][0], accW[2 * kc][1]); \
      w.u[1] = pk(accW[2 * kc][2], accW[2 * kc][3]); \
      w.u[2] = pk(accW[2 * kc + 1][0], accW[2 * kc + 1][1]); \
      w.u[3] = pk(accW[2 * kc + 1][2], accW[2 * kc + 1][3]); \
      att = __builtin_amdgcn_mfma_f32_16x16x32_bf16(fX[kc], w.v, att, 0, 0, 0); \
    } \
    return att; \
  };

// feat MFMA for one c-quarter (tn literal!) -> Fb (stride 33, XOR ^g)
#define FEATQ(tn, FB) do { \
  _Pragma("unroll") \
  for (int l = 0; l < 4; ++l) { \
    int wq = 4 * wv + l; \
    UF8 fP; fP.u[0] = Pp[l][0]; fP.u[1] = Pp[l][1]; fP.u[2] = 0; fP.u[3] = 0; \
    UF8 fV; fV.u[0] = vp[l][2 * (tn)]; fV.u[1] = vp[l][2 * (tn) + 1]; fV.u[2] = 0; fV.u[3] = 0; \
    v4f ft = {0.f, 0.f, 0.f, 0.f}; \
    ft = __builtin_amdgcn_mfma_f32_16x16x32_bf16(fP.v, fV.v, ft, 0, 0, 0); \
    _Pragma("unroll") \
    for (int j = 0; j < 4; ++j) { \
      int r = (4 * g + j) * 16 + i16; \
      (FB)[r * 33 + (wq ^ g)] = ft[j]; \
    } \
  } \
} while (0)

// ---------------- pass 1: Z partials + att(f16) + v(bf16 B-fragments) ----------------
__global__ __launch_bounds__(512) void pass1_z(
    const float* __restrict__ x, const float* __restrict__ bv,
    const unsigned* __restrict__ ws, float* __restrict__ zp,
    unsigned* __restrict__ attw, unsigned* __restrict__ vw) {
  __shared__ __align__(16) unsigned char Xd[2][65792];      // 131584 B
  __shared__ unsigned Wm[4608];                             // 18432 B  (total 150016)

  const int tid = (int)threadIdx.x;
  const int lane = tid & 63, wv = tid >> 6;
  const int i16 = lane & 15, g = lane >> 4;
  DECODE256();

  for (int o = tid; o < 4608; o += 512) Wm[o] = ws[o];
  const float beta = ((const float*)ws)[4608];
  float bvv[4];
  #pragma unroll
  for (int tn = 0; tn < 4; ++tn) bvv[tn] = bv[i16 + 16 * tn];

  STAGE_DEFS();
  LOADX_DEF();
  LDF_DEF();
  ATTOF_DEF();

  auto doLoc = [&](const unsigned char* cur, int d, int l, float Zl[4]) {
    v8s fX[2]; loadX(cur, 4 * wv + l, fX);
    v4f att = attOf(fX);
    float s0 = att[0] * S2L, s1 = att[1] * S2L;
    float s2 = att[2] * S2L, s3 = att[3] * S2L;
    Zl[0] += exp2f(s0); Zl[1] += exp2f(s1);
    Zl[2] += exp2f(s2); Zl[3] += exp2f(s3);
    const size_t ls = ((size_t)((b << 5) + h) * 32 + d) * 32 + (4 * wv + l);
    uint2 av; av.x = pkh(s0, s1); av.y = pkh(s2, s3);
    *(uint2*)(attw + ls * 128 + lane * 2) = av;
    // v = X~ @ Wv~ : store exact B-fragment dwords pass2 needs
    uint4 o0, o1;
    {
      v4f a;
      a = (v4f){bvv[0], bvv[0], bvv[0], bvv[0]};
      a = __builtin_amdgcn_mfma_f32_16x16x32_bf16(fX[0], ldf(10), a, 0, 0, 0);
      a = __builtin_amdgcn_mfma_f32_16x16x32_bf16(fX[1], ldf(11), a, 0, 0, 0);
      o0.x = pk(a[0], a[1]); o0.y = pk(a[2], a[3]);
      a = (v4f){bvv[1], bvv[1], bvv[1], bvv[1]};
      a = __builtin_amdgcn_mfma_f32_16x16x32_bf16(fX[0], ldf(12), a, 0, 0, 0);
      a = __builtin_amdgcn_mfma_f32_16x16x32_bf16(fX[1], ldf(13), a, 0, 0, 0);
      o0.z = pk(a[0], a[1]); o0.w = pk(a[2], a[3]);
      a = (v4f){bvv[2], bvv[2], bvv[2], bvv[2]};
      a = __builtin_amdgcn_mfma_f32_16x16x32_bf16(fX[0], ldf(14), a, 0, 0, 0);
      a = __builtin_amdgcn_mfma_f32_16x16x32_bf16(fX[1], ldf(15), a, 0, 0, 0);
      o1.x = pk(a[0], a[1]); o1.y = pk(a[2], a[3]);
      a = (v4f){bvv[3], bvv[3], bvv[3], bvv[3]};
      a = __builtin_amdgcn_mfma_f32_16x16x32_bf16(fX[0], ldf(16), a, 0, 0, 0);
      a = __builtin_amdgcn_mfma_f32_16x16x32_bf16(fX[1], ldf(17), a, 0, 0, 0);
      o1.z = pk(a[0], a[1]); o1.w = pk(a[2], a[3]);
    }
    // FIX (R17 bug): stride is 128 uint4 (2048 B) per loc-slice, not 32
    uint4* vpd = (uint4*)vw + ls * 128 + lane * 2;
    vpd[0] = o0; vpd[1] = o1;
  };

  float Z[4][4] = {};
  issueH(d0, 0); writeH(Xd[0], 0);
  issueH(d0, 1); writeH(Xd[0], 1);
  __syncthreads();
  for (int ii = 0; ii < 8; ++ii) {
    const int d = d0 + ii;
    unsigned char* cur = Xd[ii & 1];
    unsigned char* nxt = Xd[(ii & 1) ^ 1];
    if (ii < 7) issueH(d + 1, 0);
    doLoc(cur, d, 0, Z[0]);
    doLoc(cur, d, 1, Z[1]);
    if (ii < 7) { writeH(nxt, 0); issueH(d + 1, 1); }
    doLoc(cur, d, 2, Z[2]);
    doLoc(cur, d, 3, Z[3]);
    if (ii < 7) writeH(nxt, 1);
    __syncthreads();
  }
  const int locg = b * 1024 + h * 32 + 4 * wv;
  #pragma unroll
  for (int l = 0; l < 4; ++l)
    #pragma unroll
    for (int j = 0; j < 4; ++j)
      zp[(((size_t)dc * 2048 + locg + l) << 8) + (4 * g + j) * 16 + i16] = Z[l][j];
}

// ---------------- pass 2: NO x. Stream att+v fragments -> feat -> out ----------------
__global__ __launch_bounds__(512) void pass2_out(
    const float* __restrict__ zp, const unsigned* __restrict__ attw,
    const unsigned* __restrict__ vw, float* __restrict__ out) {
  __shared__ float Fb2[2][8448];                            // 67584 B total

  const int tid = (int)threadIdx.x;
  const int lane = tid & 63, wv = tid >> 6;
  const int i16 = lane & 15, g = lane >> 4;
  DECODE512();

  // 1/Z from the 4 pass1 chunk partials
  float iZ[4][4];
  #pragma unroll
  for (int l = 0; l < 4; ++l) {
    const int locg = b * 1024 + h * 32 + 4 * wv + l;
    #pragma unroll
    for (int j = 0; j < 4; ++j) {
      float s = 0.f;
      #pragma unroll
      for (int c2 = 0; c2 < 4; ++c2)
        s += zp[(((size_t)c2 * 2048 + locg) << 8) + (4 * g + j) * 16 + i16];
      iZ[l][j] = 1.f / s;
    }
  }

  auto lsOf = [&](int d, int l) -> size_t {
    return ((size_t)((b << 5) + h) * 32 + d) * 32 + (4 * wv + l);
  };
  auto loadAtt = [&](int d, uint2* dst) {
    #pragma unroll
    for (int l = 0; l < 4; ++l)
      dst[l] = *(const uint2*)(attw + lsOf(d, l) * 128 + lane * 2);
  };
  auto loadV = [&](int d, uint4* a4, uint4* b4) {
    #pragma unroll
    for (int l = 0; l < 4; ++l) {
      // FIX (R17 bug): stride 128 uint4 per loc-slice
      const uint4* vpd = (const uint4*)vw + lsOf(d, l) * 128 + lane * 2;
      a4[l] = vpd[0]; b4[l] = vpd[1];
    }
  };

  auto storeQ = [&](int tn, int d, const float* FB) {
    float* op = out + base0 + (size_t)d * 1024 + (size_t)(16 * tn) * NSP;
    const int w4 = tid & 7, rr = tid >> 3;
    #pragma unroll
    for (int it = 0; it < 4; ++it) {
      int r = (it << 6) + rr;
      const float* fp = &FB[r * 33 + (w4 << 2)];
      float4 val;
      val.x = fp[0 ^ it]; val.y = fp[1 ^ it]; val.z = fp[2 ^ it]; val.w = fp[3 ^ it];
      *(float4*)(op + (size_t)((r >> 4) * 64 + (r & 15)) * NSP + (w4 << 2)) = val;
    }
  };

  // prologue
  uint2 ar[4]; uint4 vA[4], vB[4];
  loadAtt(d0, ar);
  loadV(d0, vA, vB);
  for (int ii = 0; ii < 4; ++ii) {
    const int d = d0 + ii;
    unsigned Pp[4][2], vp[4][8];
    #pragma unroll
    for (int l = 0; l < 4; ++l) {
      float2 f01 = uph(ar[l].x), f23 = uph(ar[l].y);
      float p0 = exp2f(f01.x) * iZ[l][0], p1 = exp2f(f01.y) * iZ[l][1];
      float p2 = exp2f(f23.x) * iZ[l][2], p3 = exp2f(f23.y) * iZ[l][3];
      Pp[l][0] = pk(p0, p1); Pp[l][1] = pk(p2, p3);
      vp[l][0] = vA[l].x; vp[l][1] = vA[l].y; vp[l][2] = vA[l].z; vp[l][3] = vA[l].w;
      vp[l][4] = vB[l].x; vp[l][5] = vB[l].y; vp[l][6] = vB[l].z; vp[l][7] = vB[l].w;
    }
    uint2 arN[4]; uint4 vAn[4], vBn[4];
    FEATQ(0, Fb2[0]);
    __syncthreads();                       // also orders prev storeQ(3) reads of Fb2[1]
    storeQ(0, d, Fb2[0]);
    if (ii < 3) { loadAtt(d + 1, arN); loadV(d + 1, vAn, vBn); }  // fly across rest
    FEATQ(1, Fb2[1]);
    __syncthreads();
    storeQ(1, d, Fb2[1]); FEATQ(2, Fb2[0]);
    __syncthreads();
    storeQ(2, d, Fb2[0]); FEATQ(3, Fb2[1]);
    __syncthreads();
    storeQ(3, d, Fb2[1]);
    if (ii < 3) {
      #pragma unroll
      for (int l = 0; l < 4; ++l) { ar[l] = arN[l]; vA[l] = vAn[l]; vB[l] = vBn[l]; }
    }
  }
}

extern "C" void kernel_launch(void* const* d_in, const int* in_sizes, int n_in,
                              void* d_out, int out_size, void* d_ws, size_t ws_size,
                              hipStream_t stream) {
  const float* x  = (const float*)d_in[0];
  const float* Wk = (const float*)d_in[1];
  const float* bk = (const float*)d_in[2];
  const float* Wq = (const float*)d_in[3];
  const float* bq = (const float*)d_in[4];
  const float* Wv = (const float*)d_in[5];
  const float* bv = (const float*)d_in[6];
  float* out = (float*)d_out;
  unsigned* ws = (unsigned*)d_ws;
  float*    zp   = (float*)((char*)d_ws + WS_ZP_B);
  unsigned* attw = (unsigned*)((char*)d_ws + WS_ATT_B);
  unsigned* vw   = (unsigned*)((char*)d_ws + WS_V_B);

  prep_kernel<<<1, 512, 0, stream>>>(Wk, bk, Wq, bq, Wv, ws);
  pass1_z<<<256, 512, 0, stream>>>(x, bv, ws, zp, attw, vw);
  pass2_out<<<512, 512, 0, stream>>>(zp, attw, vw, out);
}